// Round 15
// baseline (592.970 us; speedup 1.0000x reference)
//
#include <hip/hip_runtime.h>
#include <hip/hip_bf16.h>

#define T_TOK 8192
#define DIM   1024
#define HID   4096
#define NE    8
#define RCAP  (T_TOK * 2 + 256)

typedef unsigned short u16;
typedef unsigned int   u32;
typedef float  f32x4 __attribute__((ext_vector_type(4)));
typedef __bf16 bf16x8 __attribute__((ext_vector_type(8)));

__device__ __forceinline__ u16 f2bf(float f) {
    u32 u = __builtin_bit_cast(u32, f);
    return (u16)((u + 0x7FFFu + ((u >> 16) & 1u)) >> 16);
}
__device__ __forceinline__ u32 pk2(float a, float b) {
    return (u32)f2bf(a) | ((u32)f2bf(b) << 16);
}
__device__ __forceinline__ float bf2f(u16 u) {
    return __builtin_bit_cast(float, (u32)u << 16);
}

#define GLOAD_LDS16(g, l) \
    __builtin_amdgcn_global_load_lds((const __attribute__((address_space(1))) u32*)(g), \
                                     (__attribute__((address_space(3))) u32*)(l), 16, 0, 0)

// ---------------- router: one wave per token; counters padded (1/line) ----------------
__global__ __launch_bounds__(256) void router_kernel(
    const float* __restrict__ x, const float* __restrict__ gw,
    int* __restrict__ tok_e, float* __restrict__ tok_w, int* __restrict__ cnt)
{
    int wid  = threadIdx.x >> 6;
    int lane = threadIdx.x & 63;
    int t = blockIdx.x * 4 + wid;

    const float4* xp = (const float4*)(x + (size_t)t * DIM);
    float4 xv[4];
    #pragma unroll
    for (int c = 0; c < 4; ++c) xv[c] = xp[c * 64 + lane];

    float r[NE];
    #pragma unroll
    for (int e = 0; e < NE; ++e) {
        const float4* gp = (const float4*)(gw + e * DIM);
        float acc = 0.f;
        #pragma unroll
        for (int c = 0; c < 4; ++c) {
            float4 g = gp[c * 64 + lane];
            acc += xv[c].x * g.x + xv[c].y * g.y + xv[c].z * g.z + xv[c].w * g.w;
        }
        r[e] = acc;
    }
    #pragma unroll
    for (int s = 1; s < 64; s <<= 1) {
        #pragma unroll
        for (int e = 0; e < NE; ++e) r[e] += __shfl_xor(r[e], s);
    }
    if (lane == 0) {
        int e0 = 0; float l0 = r[0];
        #pragma unroll
        for (int e = 1; e < NE; ++e) if (r[e] > l0) { l0 = r[e]; e0 = e; }
        int e1 = -1; float l1 = -3e38f;
        #pragma unroll
        for (int e = 0; e < NE; ++e) if (e != e0 && r[e] > l1) { l1 = r[e]; e1 = e; }
        float d  = __expf(l1 - l0);          // <= 1
        float w0 = 1.f / (1.f + d);
        float w1 = d * w0;
        tok_e[t * 2]     = e0;  tok_e[t * 2 + 1] = e1;
        tok_w[t * 2]     = w0;  tok_w[t * 2 + 1] = w1;
        atomicAdd(&cnt[e0 * 16], 1);
        atomicAdd(&cnt[e1 * 16], 1);
    }
}

// ---------------- prefix: bases + item cumsums ----------------
__global__ void prefix_kernel(const int* __restrict__ cnt, int* __restrict__ base,
                              int* __restrict__ qmeta)
{
    if (threadIdx.x == 0) {
        int* cum1 = qmeta;        // [9]
        int* cum2 = qmeta + 16;   // [9]
        int s = 0, c1 = 0, c2 = 0;
        cum1[0] = 0; cum2[0] = 0;
        for (int e = 0; e < NE; ++e) {
            base[e] = s; s += cnt[e * 16];
            int mts = (cnt[e * 16] + 255) >> 8;
            c1 += mts * (HID / 256);       cum1[e + 1] = c1;
            c2 += mts * 2 * (DIM / 256);   cum2[e + 1] = c2;
        }
        qmeta[32] = 0;   // qcur (shared by G1+G2 phases)
    }
}

// ---------------- scatter: 32 tokens/block, LDS ranks, 8 padded atomics/block ----------------
__global__ __launch_bounds__(256) void scatter_kernel(
    const float* __restrict__ x, const int* __restrict__ tok_e,
    const int* __restrict__ base, int* __restrict__ cursor,
    int* __restrict__ invrow, u16* __restrict__ A1)
{
    __shared__ int hist[NE], gbase[NE], rows[64];
    int b  = blockIdx.x;
    int t0 = b * 32;
    if (threadIdx.x < NE) hist[threadIdx.x] = 0;
    __syncthreads();
    if (threadIdx.x == 0) {
        for (int s = 0; s < 64; ++s) {
            int e = tok_e[t0 * 2 + s];
            rows[s] = hist[e]++;
        }
        for (int e = 0; e < NE; ++e)
            gbase[e] = atomicAdd(&cursor[e * 16], hist[e]);
        for (int s = 0; s < 64; ++s) {
            int e = tok_e[t0 * 2 + s];
            int row = base[e] + gbase[e] + rows[s];
            rows[s] = row;
            invrow[t0 * 2 + s] = row;
        }
    }
    __syncthreads();
    int i = threadIdx.x;
    for (int t = 0; t < 32; ++t) {
        float4 xv = ((const float4*)(x + (size_t)(t0 + t) * DIM))[i];
        u32 p0 = pk2(xv.x, xv.y);
        u32 p1 = pk2(xv.z, xv.w);
        int r0 = rows[2 * t], r1 = rows[2 * t + 1];
        u32* d0 = (u32*)(A1 + (size_t)r0 * DIM) + i * 2;
        d0[0] = p0; d0[1] = p1;
        u32* d1 = (u32*)(A1 + (size_t)r1 * DIM) + i * 2;
        d1[0] = p0; d1[1] = p1;
    }
}

// ---------------- fp32 -> bf16 weight conversion ----------------
__global__ __launch_bounds__(256) void convw_kernel(
    const float* __restrict__ W1, const float* __restrict__ W2,
    u16* __restrict__ W1b, u16* __restrict__ W2b)
{
    const size_t n8 = (size_t)NE * HID * DIM / 8;
    size_t stride = (size_t)gridDim.x * blockDim.x;
    for (size_t i = blockIdx.x * (size_t)blockDim.x + threadIdx.x; i < 2 * n8; i += stride) {
        const float* src = (i < n8) ? W1 : W2;
        u16*         dst = (i < n8) ? W1b : W2b;
        size_t j = (i < n8) ? i : i - n8;
        float4 a = ((const float4*)src)[j * 2];
        float4 b = ((const float4*)src)[j * 2 + 1];
        uint4 o;
        o.x = pk2(a.x, a.y); o.y = pk2(a.z, a.w);
        o.z = pk2(b.x, b.y); o.w = pk2(b.z, b.w);
        ((uint4*)dst)[j] = o;
    }
}

// ---------------- FUSED persistent grouped GEMM (G1 then G2 via one queue) ----------------
// Inner loop = R7/R14-exact (best measured 214 us/GEMM): 256x256, BK=32,
// 8 waves, 4-slot ring, depth-2 staging, counted vmcnt(4), 4-phase cadence,
// LDS XOR-swizzle (0 conflicts). Runtime dims per item (G1: K=1024,N=4096;
// G2: K=2048 split, N=1024, bf16 partial outputs).
// Dependency: G1 item (e,nt,mt) completion -> release fence -> dep[e][mt]++.
// G2 item (e,ks,nt,mt) spins dep[e][mt]==16 -> acquire fence. Queue hands out
// all G1 items before any G2 item and G1 never spins -> no deadlock; grid=256
// at 1 block/CU so all blocks are co-resident.
__global__ __launch_bounds__(512, 2) void moe_gemm_fused(
    const u16* __restrict__ A1, const u16* __restrict__ W1b, const float* __restrict__ b1,
    u16* __restrict__ hbuf, const u16* __restrict__ W2b, const float* __restrict__ b2,
    u16* __restrict__ Y0, u16* __restrict__ Y1,
    const int* __restrict__ cnt, const int* __restrict__ base,
    const int* __restrict__ cum1, const int* __restrict__ cum2,
    int* __restrict__ qcur, int* __restrict__ dep)
{
    __shared__ u16 lds[4 * 16384];        // 4 ring slots x (A 256x32 + B 256x32)
    __shared__ int sitem;

    int tid  = threadIdx.x;
    int lane = tid & 63;
    int w    = tid >> 6;
    int wr   = w >> 2, wc = w & 3;

    int xc   = (lane >> 1) & 3;
    int aOff = (wr * 128 + (lane & 15)) * 32 + (((lane >> 4) ^ xc) * 8);
    int bOff = 8192 + (wc * 64 + (lane & 15)) * 32 + (((lane >> 4) ^ xc) * 8);

    int srow = w * 16 + (lane >> 2);      // 0..127
    int scol = (((lane & 3) ^ ((lane >> 3) & 3)) * 8);
    u16* dA0 = lds + (w * 64 + lane) * 8;
    u16* dA1 = dA0 + 4096;
    u16* dB0 = dA0 + 8192;
    u16* dB1 = dA0 + 12288;

    int n1 = cum1[NE], n2 = cum2[NE], total = n1 + n2;
    int lastDep = -1;                     // tid0-only: pending G1 completion

    for (;;) {
        __syncthreads();                  // all waves' epilogue stores vmcnt-drained
        if (tid == 0) {
            if (lastDep >= 0) {           // release: H of previous G1 item visible
                __threadfence();
                atomicAdd(&dep[lastDep], 1);
                lastDep = -1;
            }
            int p = atomicAdd(qcur, 1);
            int it = -1;
            if (p < total) {
                if (p < n1) {             // ---- G1 item ----
                    int e = 0;
                    while (p >= cum1[e + 1]) ++e;
                    int r   = p - cum1[e];
                    int mts = (cnt[e * 16] + 255) >> 8;
                    int nt = r / mts, mt = r - nt * mts;
                    it = (e << 16) | (nt << 8) | mt;
                } else {                  // ---- G2 item ----
                    int q = p - n1;
                    int e = 0;
                    while (q >= cum2[e + 1]) ++e;
                    int r   = q - cum2[e];
                    int mts = (cnt[e * 16] + 255) >> 8;
                    int ksnt = r / mts, mt = r - ksnt * mts;
                    int ks = ksnt >> 2, nt = ksnt & 3;
                    it = (1 << 26) | (e << 16) | (ks << 12) | (nt << 8) | mt;
                    while (atomicAdd(&dep[e * 64 + mt], 0) < 16)   // H rows ready?
                        __builtin_amdgcn_s_sleep(2);
                    __threadfence();      // acquire: invalidate stale H lines
                }
            }
            sitem = it;
        }
        __syncthreads();
        int item = sitem;
        if (item < 0) break;

        bool isG2 = (item >> 26) & 1;
        int e  = (item >> 16) & 255;
        int ks = (item >> 12) & 15;
        int nt = (item >> 8) & 15;
        int mt = item & 255;
        int ce = cnt[e * 16];
        int m0 = base[e] + mt * 256;
        int n0 = nt * 256;

        const u16 *Ap, *Bp; const float* biasp; int KD, ND, KLEN;
        if (!isG2) { Ap = A1;   Bp = W1b + (size_t)e * HID * DIM; biasp = b1 + e * HID; KD = DIM; ND = HID; KLEN = DIM; }
        else       { Ap = hbuf; Bp = W2b + (size_t)e * DIM * HID; biasp = b2 + e * DIM; KD = HID; ND = DIM; KLEN = HID / 2; }
        int k0  = ks * KLEN;
        int NI  = (KLEN / 32) / 2;

        const u16* aS0 = Ap + (size_t)(m0 + srow) * KD + k0 + scol;
        const u16* aS1 = aS0 + (size_t)128 * KD;
        const u16* bS0 = Bp + (size_t)(n0 + srow) * KD + k0 + scol;
        const u16* bS1 = bS0 + (size_t)128 * KD;

#define STAGE_AB(kt_) do { int b_ = ((kt_) & 3) * 16384; size_t ko_ = (size_t)(kt_) * 32; \
        GLOAD_LDS16(aS0 + ko_, dA0 + b_); GLOAD_LDS16(aS1 + ko_, dA1 + b_); } while (0)
#define STAGE_BB(kt_) do { int b_ = ((kt_) & 3) * 16384; size_t ko_ = (size_t)(kt_) * 32; \
        GLOAD_LDS16(bS0 + ko_, dB0 + b_); GLOAD_LDS16(bS1 + ko_, dB1 + b_); } while (0)

        f32x4 acc[8][4];
        #pragma unroll
        for (int m = 0; m < 8; ++m)
            #pragma unroll
            for (int n = 0; n < 4; ++n)
                #pragma unroll
                for (int i = 0; i < 4; ++i) acc[m][n][i] = 0.f;

        // prologue: tiles 0,1 (8 loads); tile0 landed at vmcnt(4)
        STAGE_AB(0); STAGE_BB(0); STAGE_AB(1); STAGE_BB(1);
        asm volatile("s_waitcnt vmcnt(4)" ::: "memory");
        __builtin_amdgcn_s_barrier();

        for (int i = 0; i < NI; ++i) {
            int t0  = 2 * i, t1 = 2 * i + 1;
            int bo0 = (t0 & 3) * 16384, bo1 = (t1 & 3) * 16384;
            bool st = (i + 1 < NI);
            bf16x8 am[4], bn[4];

            // ---------- phase 1: tile t0, m 0-3 (+ all bn) ----------
            #pragma unroll
            for (int m = 0; m < 4; ++m) am[m] = *(const bf16x8*)(lds + bo0 + aOff + m * 512);
            #pragma unroll
            for (int n = 0; n < 4; ++n) bn[n] = *(const bf16x8*)(lds + bo0 + bOff + n * 512);
            if (st) STAGE_AB(t0 + 2);
            __builtin_amdgcn_s_barrier();
            asm volatile("s_waitcnt lgkmcnt(0)" ::: "memory");
            __builtin_amdgcn_sched_barrier(0);
            __builtin_amdgcn_s_setprio(1);
            #pragma unroll
            for (int m = 0; m < 4; ++m)
                #pragma unroll
                for (int n = 0; n < 4; ++n)
                    acc[m][n] = __builtin_amdgcn_mfma_f32_16x16x32_bf16(am[m], bn[n], acc[m][n], 0, 0, 0);
            __builtin_amdgcn_s_setprio(0);
            __builtin_amdgcn_sched_barrier(0);
            __builtin_amdgcn_s_barrier();

            // ---------- phase 2: tile t0, m 4-7 ----------
            #pragma unroll
            for (int m = 0; m < 4; ++m) am[m] = *(const bf16x8*)(lds + bo0 + aOff + (m + 4) * 512);
            if (st) STAGE_BB(t0 + 2);
            __builtin_amdgcn_s_barrier();
            asm volatile("s_waitcnt lgkmcnt(0)" ::: "memory");
            __builtin_amdgcn_sched_barrier(0);
            __builtin_amdgcn_s_setprio(1);
            #pragma unroll
            for (int m = 0; m < 4; ++m)
                #pragma unroll
                for (int n = 0; n < 4; ++n)
                    acc[m + 4][n] = __builtin_amdgcn_mfma_f32_16x16x32_bf16(am[m], bn[n], acc[m + 4][n], 0, 0, 0);
            __builtin_amdgcn_s_setprio(0);
            __builtin_amdgcn_sched_barrier(0);
            if (st) asm volatile("s_waitcnt vmcnt(4)" ::: "memory");   // tile t1 landed
            else    asm volatile("s_waitcnt vmcnt(0)" ::: "memory");
            __builtin_amdgcn_s_barrier();

            // ---------- phase 3: tile t1, m 0-3 (+ all bn) ----------
            #pragma unroll
            for (int m = 0; m < 4; ++m) am[m] = *(const bf16x8*)(lds + bo1 + aOff + m * 512);
            #pragma unroll
            for (int n = 0; n < 4; ++n) bn[n] = *(const bf16x8*)(lds + bo1 + bOff + n * 512);
            if (st) STAGE_AB(t1 + 2);
            __builtin_amdgcn_s_barrier();
            asm volatile("s_waitcnt lgkmcnt(0)" ::: "memory");
            __builtin_amdgcn_sched_barrier(0);
            __builtin_amdgcn_s_setprio(1);
            #pragma unroll
            for (int m = 0; m < 4; ++m)
                #pragma unroll
                for (int n = 0; n < 4; ++n)
                    acc[m][n] = __builtin_amdgcn_mfma_f32_16x16x32_bf16(am[m], bn[n], acc[m][n], 0, 0, 0);
            __builtin_amdgcn_s_setprio(0);
            __builtin_amdgcn_sched_barrier(0);
            __builtin_amdgcn_s_barrier();

            // ---------- phase 4: tile t1, m 4-7 ----------
            #pragma unroll
            for (int m = 0; m < 4; ++m) am[m] = *(const bf16x8*)(lds + bo1 + aOff + (m + 4) * 512);
            if (st) STAGE_BB(t1 + 2);
            __builtin_amdgcn_s_barrier();
            asm volatile("s_waitcnt lgkmcnt(0)" ::: "memory");
            __builtin_amdgcn_sched_barrier(0);
            __builtin_amdgcn_s_setprio(1);
            #pragma unroll
            for (int m = 0; m < 4; ++m)
                #pragma unroll
                for (int n = 0; n < 4; ++n)
                    acc[m + 4][n] = __builtin_amdgcn_mfma_f32_16x16x32_bf16(am[m], bn[n], acc[m + 4][n], 0, 0, 0);
            __builtin_amdgcn_s_setprio(0);
            __builtin_amdgcn_sched_barrier(0);
            if (st) asm volatile("s_waitcnt vmcnt(4)" ::: "memory");   // tile t0+2 landed
            __builtin_amdgcn_s_barrier();
        }
#undef STAGE_AB
#undef STAGE_BB

        // epilogue: C/D layout col = lane&15, row = (lane>>4)*4 + reg
        #pragma unroll
        for (int m = 0; m < 8; ++m) {
            #pragma unroll
            for (int j = 0; j < 4; ++j) {
                int rr   = wr * 128 + m * 16 + (lane >> 4) * 4 + j;
                int rloc = mt * 256 + rr;
                if (rloc < ce) {
                    if (!isG2) {
                        u16* hp = hbuf + (size_t)(m0 + rr) * ND;
                        #pragma unroll
                        for (int n = 0; n < 4; ++n) {
                            int gcol = n0 + wc * 64 + n * 16 + (lane & 15);
                            float v = acc[m][n][j] + biasp[gcol];
                            v = v > 0.f ? v : 0.f;
                            hp[gcol] = f2bf(v);
                        }
                    } else {
                        u16* yp = (ks == 0 ? Y0 : Y1) + (size_t)(m0 + rr) * ND;
                        #pragma unroll
                        for (int n = 0; n < 4; ++n) {
                            int gcol = n0 + wc * 64 + n * 16 + (lane & 15);
                            float v = acc[m][n][j];
                            if (ks == 0) v += biasp[gcol];
                            yp[gcol] = f2bf(v);
                        }
                    }
                }
            }
        }
        asm volatile("s_waitcnt vmcnt(0)" ::: "memory");   // per-wave store drain
        if (tid == 0 && !isG2) lastDep = e * 64 + mt;      // flushed at next loop top
    }
}

// ---------------- combine (bf16 partials): out = w0*(Y0[r0]+Y1[r0]) + w1*(Y0[r1]+Y1[r1]) ----------------
__global__ __launch_bounds__(256) void combine_kernel(
    const u16* __restrict__ Y0, const u16* __restrict__ Y1,
    const int* __restrict__ invrow, const float* __restrict__ tok_w,
    float* __restrict__ out)
{
    int t  = blockIdx.x;
    int r0 = invrow[t * 2], r1 = invrow[t * 2 + 1];
    float w0 = tok_w[t * 2], w1 = tok_w[t * 2 + 1];
    int i = threadIdx.x;
    ushort4 a0 = ((const ushort4*)(Y0 + (size_t)r0 * DIM))[i];
    ushort4 b0 = ((const ushort4*)(Y1 + (size_t)r0 * DIM))[i];
    ushort4 a1 = ((const ushort4*)(Y0 + (size_t)r1 * DIM))[i];
    ushort4 b1 = ((const ushort4*)(Y1 + (size_t)r1 * DIM))[i];
    float4 o;
    o.x = w0 * (bf2f(a0.x) + bf2f(b0.x)) + w1 * (bf2f(a1.x) + bf2f(b1.x));
    o.y = w0 * (bf2f(a0.y) + bf2f(b0.y)) + w1 * (bf2f(a1.y) + bf2f(b1.y));
    o.z = w0 * (bf2f(a0.z) + bf2f(b0.z)) + w1 * (bf2f(a1.z) + bf2f(b1.z));
    o.w = w0 * (bf2f(a0.w) + bf2f(b0.w)) + w1 * (bf2f(a1.w) + bf2f(b1.w));
    ((float4*)(out + (size_t)t * DIM))[i] = o;
}

extern "C" void kernel_launch(void* const* d_in, const int* in_sizes, int n_in,
                              void* d_out, int out_size, void* d_ws, size_t ws_size,
                              hipStream_t stream) {
    const float* xs = (const float*)d_in[0];
    const float* gw = (const float*)d_in[1];
    const float* W1 = (const float*)d_in[2];
    const float* b1 = (const float*)d_in[3];
    const float* W2 = (const float*)d_in[4];
    const float* b2 = (const float*)d_in[5];
    float* out = (float*)d_out;

    char* ws = (char*)d_ws;
    size_t off = 0;
    auto alloc = [&](size_t bytes) -> void* {
        off = (off + 255) & ~(size_t)255;
        void* p = ws + off;
        off += bytes;
        return p;
    };
    int*   ctrs   = (int*)alloc(2048);          // cnt[e*16] @0, cursor[e*16] @+128 ints
    int*   cnt    = ctrs;
    int*   cursor = ctrs + 128;
    int*   base   = (int*)alloc(64);
    int*   qmeta  = (int*)alloc(256);           // cum1[9], cum2[9]@16, qcur@32
    int*   dep    = (int*)alloc(2048);          // dep[e*64+mt]
    int*   tok_e  = (int*)alloc((size_t)T_TOK * 2 * 4);
    float* tok_w  = (float*)alloc((size_t)T_TOK * 2 * 4);
    int*   invrow = (int*)alloc((size_t)T_TOK * 2 * 4);
    u16*   A1     = (u16*)alloc((size_t)RCAP * DIM * 2);       // 34 MB
    u16*   W1b    = (u16*)alloc((size_t)NE * HID * DIM * 2);   // 64 MB
    u16*   W2b    = (u16*)alloc((size_t)NE * HID * DIM * 2);   // 64 MB
    u16*   hbuf   = (u16*)alloc((size_t)RCAP * HID * 2);       // 136 MB
    u16*   Ypart0 = (u16*)alloc((size_t)RCAP * DIM * 2);       // 34 MB bf16
    u16*   Ypart1 = (u16*)alloc((size_t)RCAP * DIM * 2);       // 34 MB bf16
    (void)ws_size; (void)in_sizes; (void)n_in; (void)out_size;

    hipMemsetAsync(ctrs, 0, 2048, stream);
    hipMemsetAsync(dep, 0, 2048, stream);

    router_kernel<<<T_TOK / 4, 256, 0, stream>>>(xs, gw, tok_e, tok_w, cnt);
    prefix_kernel<<<1, 64, 0, stream>>>(cnt, base, qmeta);
    scatter_kernel<<<T_TOK / 32, 256, 0, stream>>>(xs, tok_e, base, cursor, invrow, A1);
    convw_kernel<<<2048, 256, 0, stream>>>(W1, W2, W1b, W2b);

    moe_gemm_fused<<<256, 512, 0, stream>>>(
        A1, W1b, b1, hbuf, W2b, b2, Ypart0, Ypart1,
        cnt, base, qmeta, qmeta + 16, qmeta + 32, dep);

    combine_kernel<<<T_TOK, 256, 0, stream>>>(Ypart0, Ypart1, invrow, tok_w, out);
}

// Round 16
// 555.985 us; speedup vs baseline: 1.0665x; 1.0665x over previous
//
#include <hip/hip_runtime.h>
#include <hip/hip_bf16.h>

#define T_TOK 8192
#define DIM   1024
#define HID   4096
#define NE    8
#define RCAP  (T_TOK * 2 + 256)

typedef unsigned short u16;
typedef unsigned int   u32;
typedef float  f32x4 __attribute__((ext_vector_type(4)));
typedef __bf16 bf16x8 __attribute__((ext_vector_type(8)));

__device__ __forceinline__ u16 f2bf(float f) {
    u32 u = __builtin_bit_cast(u32, f);
    return (u16)((u + 0x7FFFu + ((u >> 16) & 1u)) >> 16);
}
__device__ __forceinline__ u32 pk2(float a, float b) {
    return (u32)f2bf(a) | ((u32)f2bf(b) << 16);
}
__device__ __forceinline__ float bf2f(u16 u) {
    return __builtin_bit_cast(float, (u32)u << 16);
}

#define GLOAD_LDS16(g, l) \
    __builtin_amdgcn_global_load_lds((const __attribute__((address_space(1))) u32*)(g), \
                                     (__attribute__((address_space(3))) u32*)(l), 16, 0, 0)

// ---------------- router: one wave per token; counters padded (1/line) ----------------
__global__ __launch_bounds__(256) void router_kernel(
    const float* __restrict__ x, const float* __restrict__ gw,
    int* __restrict__ tok_e, float* __restrict__ tok_w, int* __restrict__ cnt)
{
    int wid  = threadIdx.x >> 6;
    int lane = threadIdx.x & 63;
    int t = blockIdx.x * 4 + wid;

    const float4* xp = (const float4*)(x + (size_t)t * DIM);
    float4 xv[4];
    #pragma unroll
    for (int c = 0; c < 4; ++c) xv[c] = xp[c * 64 + lane];

    float r[NE];
    #pragma unroll
    for (int e = 0; e < NE; ++e) {
        const float4* gp = (const float4*)(gw + e * DIM);
        float acc = 0.f;
        #pragma unroll
        for (int c = 0; c < 4; ++c) {
            float4 g = gp[c * 64 + lane];
            acc += xv[c].x * g.x + xv[c].y * g.y + xv[c].z * g.z + xv[c].w * g.w;
        }
        r[e] = acc;
    }
    #pragma unroll
    for (int s = 1; s < 64; s <<= 1) {
        #pragma unroll
        for (int e = 0; e < NE; ++e) r[e] += __shfl_xor(r[e], s);
    }
    if (lane == 0) {
        int e0 = 0; float l0 = r[0];
        #pragma unroll
        for (int e = 1; e < NE; ++e) if (r[e] > l0) { l0 = r[e]; e0 = e; }
        int e1 = -1; float l1 = -3e38f;
        #pragma unroll
        for (int e = 0; e < NE; ++e) if (e != e0 && r[e] > l1) { l1 = r[e]; e1 = e; }
        float d  = __expf(l1 - l0);          // <= 1
        float w0 = 1.f / (1.f + d);
        float w1 = d * w0;
        tok_e[t * 2]     = e0;  tok_e[t * 2 + 1] = e1;
        tok_w[t * 2]     = w0;  tok_w[t * 2 + 1] = w1;
        atomicAdd(&cnt[e0 * 16], 1);
        atomicAdd(&cnt[e1 * 16], 1);
    }
}

// ---------------- prefix: bases + item cumsums ----------------
__global__ void prefix_kernel(const int* __restrict__ cnt, int* __restrict__ base,
                              int* __restrict__ qmeta)
{
    if (threadIdx.x == 0) {
        int* cum1 = qmeta;        // [9]
        int* cum2 = qmeta + 16;   // [9]
        int s = 0, c1 = 0, c2 = 0;
        cum1[0] = 0; cum2[0] = 0;
        for (int e = 0; e < NE; ++e) {
            base[e] = s; s += cnt[e * 16];
            int mts = (cnt[e * 16] + 255) >> 8;
            c1 += mts * (HID / 256);       cum1[e + 1] = c1;
            c2 += mts * 2 * (DIM / 256);   cum2[e + 1] = c2;
        }
        qmeta[32] = 0;   // qcur1
        qmeta[33] = 0;   // qcur2
    }
}

// ---------------- scatter: 32 tokens/block, LDS ranks, 8 padded atomics/block ----------------
__global__ __launch_bounds__(256) void scatter_kernel(
    const float* __restrict__ x, const int* __restrict__ tok_e,
    const int* __restrict__ base, int* __restrict__ cursor,
    int* __restrict__ invrow, u16* __restrict__ A1)
{
    __shared__ int hist[NE], gbase[NE], rows[64];
    int b  = blockIdx.x;
    int t0 = b * 32;
    if (threadIdx.x < NE) hist[threadIdx.x] = 0;
    __syncthreads();
    if (threadIdx.x == 0) {
        for (int s = 0; s < 64; ++s) {
            int e = tok_e[t0 * 2 + s];
            rows[s] = hist[e]++;
        }
        for (int e = 0; e < NE; ++e)
            gbase[e] = atomicAdd(&cursor[e * 16], hist[e]);
        for (int s = 0; s < 64; ++s) {
            int e = tok_e[t0 * 2 + s];
            int row = base[e] + gbase[e] + rows[s];
            rows[s] = row;
            invrow[t0 * 2 + s] = row;
        }
    }
    __syncthreads();
    int i = threadIdx.x;
    for (int t = 0; t < 32; ++t) {
        float4 xv = ((const float4*)(x + (size_t)(t0 + t) * DIM))[i];
        u32 p0 = pk2(xv.x, xv.y);
        u32 p1 = pk2(xv.z, xv.w);
        int r0 = rows[2 * t], r1 = rows[2 * t + 1];
        u32* d0 = (u32*)(A1 + (size_t)r0 * DIM) + i * 2;
        d0[0] = p0; d0[1] = p1;
        u32* d1 = (u32*)(A1 + (size_t)r1 * DIM) + i * 2;
        d1[0] = p0; d1[1] = p1;
    }
}

// ---------------- fp32 -> bf16 weight conversion ----------------
__global__ __launch_bounds__(256) void convw_kernel(
    const float* __restrict__ W1, const float* __restrict__ W2,
    u16* __restrict__ W1b, u16* __restrict__ W2b)
{
    const size_t n8 = (size_t)NE * HID * DIM / 8;
    size_t stride = (size_t)gridDim.x * blockDim.x;
    for (size_t i = blockIdx.x * (size_t)blockDim.x + threadIdx.x; i < 2 * n8; i += stride) {
        const float* src = (i < n8) ? W1 : W2;
        u16*         dst = (i < n8) ? W1b : W2b;
        size_t j = (i < n8) ? i : i - n8;
        float4 a = ((const float4*)src)[j * 2];
        float4 b = ((const float4*)src)[j * 2 + 1];
        uint4 o;
        o.x = pk2(a.x, a.y); o.y = pk2(a.z, a.w);
        o.z = pk2(b.x, b.y); o.w = pk2(b.z, b.w);
        ((uint4*)dst)[j] = o;
    }
}

// ---------------- persistent grouped GEMM — R7/R14-exact inner loop ----------------
// 256x256 tile, BK=32, 8 waves (2Mx4N), 4-slot LDS ring, stage depth-2 (t+2),
// counted vmcnt(4) per K-tile (drain 0 only at item tail). 4-phase-per-2-tiles
// cadence. LDS chunk XOR-swizzle (0 conflicts). Global dynamic queue.
// G2 writes bf16 partials (absmax headroom verified in R15: 0.0156 unchanged).
template<int KDIM, int NDIM, bool IS_G2>
__global__ __launch_bounds__(512, 2) void moe_gemm(
    const u16* __restrict__ A, const u16* __restrict__ B,
    const float* __restrict__ bias,
    u16* __restrict__ Hout, u16* __restrict__ Y0, u16* __restrict__ Y1,
    const int* __restrict__ cnt, const int* __restrict__ base,
    const int* __restrict__ cum, int* __restrict__ qcur)
{
    constexpr int KLEN = IS_G2 ? (KDIM / 2) : KDIM;   // split-K=2 for GEMM2
    constexpr int NKT  = KLEN / 32;                   // 32 (G1) / 64 (G2), even
    constexpr int NI   = NKT / 2;

    __shared__ u16 lds[4 * 16384];        // 4 ring slots x (A 256x32 + B 256x32)
    __shared__ int sitem;

    int tid  = threadIdx.x;
    int lane = tid & 63;
    int w    = tid >> 6;
    int wr   = w >> 2, wc = w & 3;

    // swizzled fragment-read offsets (u16 units), + slot*16384
    int xc   = (lane >> 1) & 3;
    int aOff = (wr * 128 + (lane & 15)) * 32 + (((lane >> 4) ^ xc) * 8);
    int bOff = 8192 + (wc * 64 + (lane & 15)) * 32 + (((lane >> 4) ^ xc) * 8);

    // staging: LDS dest linear; global source chunk inverse-permuted
    int srow = w * 16 + (lane >> 2);      // 0..127
    int scol = (((lane & 3) ^ ((lane >> 3) & 3)) * 8);
    u16* dA0 = lds + (w * 64 + lane) * 8;
    u16* dA1 = dA0 + 4096;
    u16* dB0 = dA0 + 8192;
    u16* dB1 = dA0 + 12288;

    int total = cum[NE];

    for (;;) {
        __syncthreads();                  // protects sitem & LDS reuse across items
        if (tid == 0) {
            int p = atomicAdd(qcur, 1);
            int it = -1;
            if (p < total) {
                int e = 0;
                while (p >= cum[e + 1]) ++e;
                int r   = p - cum[e];
                int mts = (cnt[e * 16] + 255) >> 8;
                int ks = 0, nt, mt;
                if (IS_G2) { int ksnt = r / mts; mt = r - ksnt * mts; ks = ksnt >> 2; nt = ksnt & 3; }
                else       { nt = r / mts; mt = r - nt * mts; }
                it = (e << 16) | (ks << 12) | (nt << 8) | mt;
            }
            sitem = it;
        }
        __syncthreads();
        int item = sitem;
        if (item < 0) break;

        int e  = item >> 16;
        int ks = (item >> 12) & 15;
        int nt = (item >> 8) & 15;
        int mt = item & 255;
        int ce = cnt[e * 16];
        int m0 = base[e] + mt * 256;
        int n0 = nt * 256;
        int k0 = ks * KLEN;

        const u16* aS0 = A + (size_t)(m0 + srow) * KDIM + k0 + scol;
        const u16* aS1 = aS0 + (size_t)128 * KDIM;
        const u16* bS0 = B + (size_t)e * NDIM * KDIM + (size_t)(n0 + srow) * KDIM + k0 + scol;
        const u16* bS1 = bS0 + (size_t)128 * KDIM;

#define STAGE_AB(kt_) do { int b_ = ((kt_) & 3) * 16384; size_t ko_ = (size_t)(kt_) * 32; \
        GLOAD_LDS16(aS0 + ko_, dA0 + b_); GLOAD_LDS16(aS1 + ko_, dA1 + b_); } while (0)
#define STAGE_BB(kt_) do { int b_ = ((kt_) & 3) * 16384; size_t ko_ = (size_t)(kt_) * 32; \
        GLOAD_LDS16(bS0 + ko_, dB0 + b_); GLOAD_LDS16(bS1 + ko_, dB1 + b_); } while (0)

        f32x4 acc[8][4];
        #pragma unroll
        for (int m = 0; m < 8; ++m)
            #pragma unroll
            for (int n = 0; n < 4; ++n)
                #pragma unroll
                for (int i = 0; i < 4; ++i) acc[m][n][i] = 0.f;

        // prologue: tiles 0,1 (8 loads); tile0 landed at vmcnt(4)
        STAGE_AB(0); STAGE_BB(0); STAGE_AB(1); STAGE_BB(1);
        asm volatile("s_waitcnt vmcnt(4)" ::: "memory");
        __builtin_amdgcn_s_barrier();

        for (int i = 0; i < NI; ++i) {
            int t0  = 2 * i, t1 = 2 * i + 1;
            int bo0 = (t0 & 3) * 16384, bo1 = (t1 & 3) * 16384;
            bool st = (i + 1 < NI);
            bf16x8 am[4], bn[4];

            // ---------- phase 1: tile t0, m 0-3 (+ all bn) ----------
            #pragma unroll
            for (int m = 0; m < 4; ++m) am[m] = *(const bf16x8*)(lds + bo0 + aOff + m * 512);
            #pragma unroll
            for (int n = 0; n < 4; ++n) bn[n] = *(const bf16x8*)(lds + bo0 + bOff + n * 512);
            if (st) STAGE_AB(t0 + 2);
            __builtin_amdgcn_s_barrier();
            asm volatile("s_waitcnt lgkmcnt(0)" ::: "memory");
            __builtin_amdgcn_sched_barrier(0);
            __builtin_amdgcn_s_setprio(1);
            #pragma unroll
            for (int m = 0; m < 4; ++m)
                #pragma unroll
                for (int n = 0; n < 4; ++n)
                    acc[m][n] = __builtin_amdgcn_mfma_f32_16x16x32_bf16(am[m], bn[n], acc[m][n], 0, 0, 0);
            __builtin_amdgcn_s_setprio(0);
            __builtin_amdgcn_sched_barrier(0);
            __builtin_amdgcn_s_barrier();

            // ---------- phase 2: tile t0, m 4-7 ----------
            #pragma unroll
            for (int m = 0; m < 4; ++m) am[m] = *(const bf16x8*)(lds + bo0 + aOff + (m + 4) * 512);
            if (st) STAGE_BB(t0 + 2);
            __builtin_amdgcn_s_barrier();
            asm volatile("s_waitcnt lgkmcnt(0)" ::: "memory");
            __builtin_amdgcn_sched_barrier(0);
            __builtin_amdgcn_s_setprio(1);
            #pragma unroll
            for (int m = 0; m < 4; ++m)
                #pragma unroll
                for (int n = 0; n < 4; ++n)
                    acc[m + 4][n] = __builtin_amdgcn_mfma_f32_16x16x32_bf16(am[m], bn[n], acc[m + 4][n], 0, 0, 0);
            __builtin_amdgcn_s_setprio(0);
            __builtin_amdgcn_sched_barrier(0);
            if (st) asm volatile("s_waitcnt vmcnt(4)" ::: "memory");   // tile t1 landed
            else    asm volatile("s_waitcnt vmcnt(0)" ::: "memory");
            __builtin_amdgcn_s_barrier();

            // ---------- phase 3: tile t1, m 0-3 (+ all bn) ----------
            #pragma unroll
            for (int m = 0; m < 4; ++m) am[m] = *(const bf16x8*)(lds + bo1 + aOff + m * 512);
            #pragma unroll
            for (int n = 0; n < 4; ++n) bn[n] = *(const bf16x8*)(lds + bo1 + bOff + n * 512);
            if (st) STAGE_AB(t1 + 2);
            __builtin_amdgcn_s_barrier();
            asm volatile("s_waitcnt lgkmcnt(0)" ::: "memory");
            __builtin_amdgcn_sched_barrier(0);
            __builtin_amdgcn_s_setprio(1);
            #pragma unroll
            for (int m = 0; m < 4; ++m)
                #pragma unroll
                for (int n = 0; n < 4; ++n)
                    acc[m][n] = __builtin_amdgcn_mfma_f32_16x16x32_bf16(am[m], bn[n], acc[m][n], 0, 0, 0);
            __builtin_amdgcn_s_setprio(0);
            __builtin_amdgcn_sched_barrier(0);
            __builtin_amdgcn_s_barrier();

            // ---------- phase 4: tile t1, m 4-7 ----------
            #pragma unroll
            for (int m = 0; m < 4; ++m) am[m] = *(const bf16x8*)(lds + bo1 + aOff + (m + 4) * 512);
            if (st) STAGE_BB(t1 + 2);
            __builtin_amdgcn_s_barrier();
            asm volatile("s_waitcnt lgkmcnt(0)" ::: "memory");
            __builtin_amdgcn_sched_barrier(0);
            __builtin_amdgcn_s_setprio(1);
            #pragma unroll
            for (int m = 0; m < 4; ++m)
                #pragma unroll
                for (int n = 0; n < 4; ++n)
                    acc[m + 4][n] = __builtin_amdgcn_mfma_f32_16x16x32_bf16(am[m], bn[n], acc[m + 4][n], 0, 0, 0);
            __builtin_amdgcn_s_setprio(0);
            __builtin_amdgcn_sched_barrier(0);
            if (st) asm volatile("s_waitcnt vmcnt(4)" ::: "memory");   // tile t0+2 landed
            __builtin_amdgcn_s_barrier();
        }
#undef STAGE_AB
#undef STAGE_BB

        // epilogue: C/D layout col = lane&15, row = (lane>>4)*4 + reg
        #pragma unroll
        for (int m = 0; m < 8; ++m) {
            #pragma unroll
            for (int j = 0; j < 4; ++j) {
                int rr   = wr * 128 + m * 16 + (lane >> 4) * 4 + j;
                int rloc = mt * 256 + rr;
                if (rloc < ce) {
                    if (!IS_G2) {
                        u16* hp = Hout + (size_t)(m0 + rr) * NDIM;
                        #pragma unroll
                        for (int n = 0; n < 4; ++n) {
                            int gcol = n0 + wc * 64 + n * 16 + (lane & 15);
                            float v = acc[m][n][j] + bias[e * NDIM + gcol];
                            v = v > 0.f ? v : 0.f;
                            hp[gcol] = f2bf(v);
                        }
                    } else {
                        u16* yp = (ks == 0 ? Y0 : Y1) + (size_t)(m0 + rr) * NDIM;
                        #pragma unroll
                        for (int n = 0; n < 4; ++n) {
                            int gcol = n0 + wc * 64 + n * 16 + (lane & 15);
                            float v = acc[m][n][j];
                            if (ks == 0) v += bias[e * NDIM + gcol];
                            yp[gcol] = f2bf(v);
                        }
                    }
                }
            }
        }
        asm volatile("s_waitcnt vmcnt(0)" ::: "memory");   // drain stores: ledger sound
    }
}

// ---------------- combine (bf16 partials): out = w0*(Y0[r0]+Y1[r0]) + w1*(Y0[r1]+Y1[r1]) ----------------
__global__ __launch_bounds__(256) void combine_kernel(
    const u16* __restrict__ Y0, const u16* __restrict__ Y1,
    const int* __restrict__ invrow, const float* __restrict__ tok_w,
    float* __restrict__ out)
{
    int t  = blockIdx.x;
    int r0 = invrow[t * 2], r1 = invrow[t * 2 + 1];
    float w0 = tok_w[t * 2], w1 = tok_w[t * 2 + 1];
    int i = threadIdx.x;
    ushort4 a0 = ((const ushort4*)(Y0 + (size_t)r0 * DIM))[i];
    ushort4 b0 = ((const ushort4*)(Y1 + (size_t)r0 * DIM))[i];
    ushort4 a1 = ((const ushort4*)(Y0 + (size_t)r1 * DIM))[i];
    ushort4 b1 = ((const ushort4*)(Y1 + (size_t)r1 * DIM))[i];
    float4 o;
    o.x = w0 * (bf2f(a0.x) + bf2f(b0.x)) + w1 * (bf2f(a1.x) + bf2f(b1.x));
    o.y = w0 * (bf2f(a0.y) + bf2f(b0.y)) + w1 * (bf2f(a1.y) + bf2f(b1.y));
    o.z = w0 * (bf2f(a0.z) + bf2f(b0.z)) + w1 * (bf2f(a1.z) + bf2f(b1.z));
    o.w = w0 * (bf2f(a0.w) + bf2f(b0.w)) + w1 * (bf2f(a1.w) + bf2f(b1.w));
    ((float4*)(out + (size_t)t * DIM))[i] = o;
}

extern "C" void kernel_launch(void* const* d_in, const int* in_sizes, int n_in,
                              void* d_out, int out_size, void* d_ws, size_t ws_size,
                              hipStream_t stream) {
    const float* xs = (const float*)d_in[0];
    const float* gw = (const float*)d_in[1];
    const float* W1 = (const float*)d_in[2];
    const float* b1 = (const float*)d_in[3];
    const float* W2 = (const float*)d_in[4];
    const float* b2 = (const float*)d_in[5];
    float* out = (float*)d_out;

    char* ws = (char*)d_ws;
    size_t off = 0;
    auto alloc = [&](size_t bytes) -> void* {
        off = (off + 255) & ~(size_t)255;
        void* p = ws + off;
        off += bytes;
        return p;
    };
    int*   ctrs   = (int*)alloc(2048);          // cnt[e*16] @0, cursor[e*16] @+128 ints
    int*   cnt    = ctrs;
    int*   cursor = ctrs + 128;
    int*   base   = (int*)alloc(64);
    int*   qmeta  = (int*)alloc(256);           // cum1[9], cum2[9]@16, qcur@32,33
    int*   tok_e  = (int*)alloc((size_t)T_TOK * 2 * 4);
    float* tok_w  = (float*)alloc((size_t)T_TOK * 2 * 4);
    int*   invrow = (int*)alloc((size_t)T_TOK * 2 * 4);
    u16*   A1     = (u16*)alloc((size_t)RCAP * DIM * 2);       // 34 MB
    u16*   W1b    = (u16*)alloc((size_t)NE * HID * DIM * 2);   // 64 MB
    u16*   W2b    = (u16*)alloc((size_t)NE * HID * DIM * 2);   // 64 MB
    u16*   hbuf   = (u16*)alloc((size_t)RCAP * HID * 2);       // 136 MB
    u16*   Ypart0 = (u16*)alloc((size_t)RCAP * DIM * 2);       // 34 MB bf16
    u16*   Ypart1 = (u16*)alloc((size_t)RCAP * DIM * 2);       // 34 MB bf16
    (void)ws_size; (void)in_sizes; (void)n_in; (void)out_size;

    hipMemsetAsync(ctrs, 0, 2048, stream);

    router_kernel<<<T_TOK / 4, 256, 0, stream>>>(xs, gw, tok_e, tok_w, cnt);
    prefix_kernel<<<1, 64, 0, stream>>>(cnt, base, qmeta);
    scatter_kernel<<<T_TOK / 32, 256, 0, stream>>>(xs, tok_e, base, cursor, invrow, A1);
    convw_kernel<<<2048, 256, 0, stream>>>(W1, W2, W1b, W2b);

    moe_gemm<DIM, HID, false><<<256, 512, 0, stream>>>(
        A1, W1b, b1, hbuf, nullptr, nullptr, cnt, base, qmeta, qmeta + 32);
    moe_gemm<HID, DIM, true><<<256, 512, 0, stream>>>(
        hbuf, W2b, b2, nullptr, Ypart0, Ypart1, cnt, base, qmeta + 16, qmeta + 33);

    combine_kernel<<<T_TOK, 256, 0, stream>>>(Ypart0, Ypart1, invrow, tok_w, out);
}